// Round 1
// 674.785 us; speedup vs baseline: 1.0292x; 1.0292x over previous
//
#include <hip/hip_runtime.h>

// GraphLayer: B=16384, F=50, E=64, all fp32.
//   h_out[b,f,i] = sum_j W_out[f,i,j] * h[b,f,j]
//   aggr[b,f,e]  = sum_g g[b,f,g] * h_out[b,g,e]
//   a[b,f,i]     = sum_j W_in[f,i,j] * aggr[b,f,j] + bias[i]
//
// Round 3: both kernels were LDS-read-throughput bound (per-thread tiles too
// small: 1 B LDS read per FLOP; per-CU LDS-pipe time ~143 us for aggr, ~96 us
// for field_gemm -- matches the measured 172 us with VALUBusy 43% / HBM 29%).
// Fix: field_gemm 8x8 per-thread tile (0.375 floats/FMA) with STRIDED i/b
// blocking so the pad-68 LDS rows stay conflict-free, plus float4 staging
// (was scalar). aggr: one wave per batch, 8e x 7f per-thread tile, linear LDS
// (conflict-free by construction), zeroed pad rows so the 13x4-g main loop
// needs no tail.

static constexpr int Bz  = 16384;
static constexpr int Ff  = 50;
static constexpr int Ee  = 64;
static constexpr int BT  = 128;   // batch tile for per-field GEMM
static constexpr int LDW = 68;    // padded LDS row stride (floats, 16B-aligned)

__device__ __forceinline__ void fma4(float4& a, float s, const float4& v) {
    a.x += s * v.x; a.y += s * v.y; a.z += s * v.z; a.w += s * v.w;
}

// dst[b,f,i] = sum_j W[f,i,j]*src[b,f,j] (+ bias[i]).  In-place (src==dst)
// safe: all global reads land in LDS before the barrier; stores after; each
// (b,f,:) row is owned by exactly one block.
// 128 threads, BT=128: thread tile 8 i's (i = ti + 8*ii) x 8 batches
// (bb = tb + 16*kb).  Strided blocking => per-b128 row addresses hit distinct
// bank quads (4*ti / 4*tb mod 32) with the 68-float pad: conflict-free.
__global__ __launch_bounds__(128, 2)
void field_gemm(const float* __restrict__ src, float* __restrict__ dst,
                const float* __restrict__ W, const float* __restrict__ bias) {
    __shared__ float W_lds[Ee * LDW];   // 64 x 68 floats = 17.4 KB
    __shared__ float h_lds[BT * LDW];   // 128 x 68 floats = 34.8 KB
    const int f  = blockIdx.y;
    const int b0 = blockIdx.x * BT;
    const int t  = threadIdx.x;

    // stage W[f]: 1024 float4, 8 per thread, coalesced
    const float4* Wf4 = (const float4*)(W + f * Ee * Ee);
#pragma unroll
    for (int k = 0; k < 8; ++k) {
        int q = k * 128 + t;
        *(float4*)&W_lds[(q >> 4) * LDW + (q & 15) * 4] = Wf4[q];
    }
    // stage src tile: 2048 float4, 16 per thread, coalesced per 256B row
    const float4* s4 = (const float4*)src;
#pragma unroll
    for (int k = 0; k < 16; ++k) {
        int q = k * 128 + t;
        int r = q >> 4;
        *(float4*)&h_lds[r * LDW + (q & 15) * 4] =
            s4[(b0 + r) * (Ff * Ee / 4) + f * 16 + (q & 15)];
    }
    __syncthreads();

    const int ti = t & 7;    // i = ti + 8*ii
    const int tb = t >> 3;   // bb = tb + 16*kb   (tb in 0..15)
    float acc[8][8];
#pragma unroll
    for (int ii = 0; ii < 8; ++ii)
#pragma unroll
        for (int kb = 0; kb < 8; ++kb) acc[ii][kb] = 0.f;

#pragma unroll 2
    for (int j0 = 0; j0 < Ee; j0 += 4) {
        float4 w4[8], h4[8];
#pragma unroll
        for (int ii = 0; ii < 8; ++ii)
            w4[ii] = *(const float4*)&W_lds[(ti + 8 * ii) * LDW + j0];
#pragma unroll
        for (int kb = 0; kb < 8; ++kb)
            h4[kb] = *(const float4*)&h_lds[(tb + 16 * kb) * LDW + j0];
#pragma unroll
        for (int ii = 0; ii < 8; ++ii)
#pragma unroll
            for (int kb = 0; kb < 8; ++kb) {
                acc[ii][kb] += w4[ii].x * h4[kb].x;
                acc[ii][kb] += w4[ii].y * h4[kb].y;
                acc[ii][kb] += w4[ii].z * h4[kb].z;
                acc[ii][kb] += w4[ii].w * h4[kb].w;
            }
    }

    // stores: per inst 8 rows x 32B contiguous chunks; consecutive ii fill
    // consecutive 32B of the same rows -> L2 write-combines to full lines.
#pragma unroll
    for (int ii = 0; ii < 8; ++ii) {
        const int i  = ti + 8 * ii;
        const float bv = bias ? bias[i] : 0.0f;
#pragma unroll
        for (int kb = 0; kb < 8; ++kb) {
            const int bb = tb + 16 * kb;
            dst[(b0 + bb) * (Ff * Ee) + f * Ee + i] = acc[ii][kb] + bv;
        }
    }
}

// aggr[b,f,e] = sum_g g[b,f,g] * ho[b,g,e], in place over ho (d_out).
// 128 threads = 2 waves; each wave owns one batch (b = 2*blockIdx.x + wid)
// with its own LDS region.  Per-thread tile: 8 e's (e0 = te*8) x 7 fields
// (fi = tf*7 + k, clamped).  LDS linear: ho reads are 2-way (free), g rows
// stride 50 floats -> distinct banks.  ho pad rows 50/51 and g pad floats
// 2500..2559 are zeroed so the uniform 13-step 4-g loop needs no tail
// (g "overflow" cols multiply zeroed ho rows).
static constexpr int HOP = 52 * Ee;        // 3328 floats: 50 rows + 2 pad rows
static constexpr int GPD = 2560;           // 2500 + 60 pad floats
static constexpr int WRG = HOP + GPD;      // 5888 floats per wave

__global__ __launch_bounds__(128, 2)
void aggr_inplace(const float* __restrict__ g, float* __restrict__ ho) {
    __shared__ float lds[2 * WRG];         // 47.1 KB -> 3 blocks/CU
    const int t    = threadIdx.x;
    const int wid  = t >> 6;
    const int lane = t & 63;
    const int b    = blockIdx.x * 2 + wid;
    float* ho_sh = &lds[wid * WRG];
    float* g_sh  = ho_sh + HOP;

    const float4* hosrc = (const float4*)(ho + (size_t)b * (Ff * Ee)); // 800 f4
    const float4* gsrc  = (const float4*)(g  + (size_t)b * (Ff * Ff)); // 625 f4
#pragma unroll
    for (int k = 0; k < 13; ++k) {
        int q = k * 64 + lane;
        if (q < Ff * Ee / 4) *(float4*)&ho_sh[q * 4] = hosrc[q];
    }
#pragma unroll
    for (int k = 0; k < 10; ++k) {
        int q = k * 64 + lane;
        if (q < (Ff * Ff + 3) / 4) *(float4*)&g_sh[q * 4] = gsrc[q];
    }
    // zero pads (must be zero, not garbage: garbage could be NaN/Inf and
    // NaN*0 != 0)
    *(float2*)&ho_sh[Ff * Ee + lane * 2] = make_float2(0.f, 0.f);   // rows 50,51
    if (lane < 30) *(float2*)&g_sh[Ff * Ff + lane * 2] = make_float2(0.f, 0.f);
    __syncthreads();

    const int te = lane & 7;
    const int tf = lane >> 3;
    const int e0 = te * 8;
    float4 acc[7][2];
#pragma unroll
    for (int k = 0; k < 7; ++k) {
        acc[k][0] = make_float4(0.f, 0.f, 0.f, 0.f);
        acc[k][1] = make_float4(0.f, 0.f, 0.f, 0.f);
    }

#pragma unroll 2
    for (int g0 = 0; g0 < 52; g0 += 4) {
        float4 ho4[4][2];
#pragma unroll
        for (int q = 0; q < 4; ++q) {
            ho4[q][0] = *(const float4*)&ho_sh[(g0 + q) * Ee + e0];
            ho4[q][1] = *(const float4*)&ho_sh[(g0 + q) * Ee + e0 + 4];
        }
#pragma unroll
        for (int k = 0; k < 7; ++k) {
            int fi = tf * 7 + k;
            fi = (fi < Ff) ? fi : (Ff - 1);   // clamp; duplicate rows not stored
            const float2 ga = *(const float2*)&g_sh[fi * Ff + g0];
            const float2 gb = *(const float2*)&g_sh[fi * Ff + g0 + 2];
            fma4(acc[k][0], ga.x, ho4[0][0]); fma4(acc[k][1], ga.x, ho4[0][1]);
            fma4(acc[k][0], ga.y, ho4[1][0]); fma4(acc[k][1], ga.y, ho4[1][1]);
            fma4(acc[k][0], gb.x, ho4[2][0]); fma4(acc[k][1], gb.x, ho4[2][1]);
            fma4(acc[k][0], gb.y, ho4[3][0]); fma4(acc[k][1], gb.y, ho4[3][1]);
        }
    }

    float* hb = ho + (size_t)b * (Ff * Ee);
#pragma unroll
    for (int k = 0; k < 7; ++k) {
        const int fi = tf * 7 + k;          // unclamped for the store guard
        if (fi < Ff) {
            *(float4*)&hb[fi * Ee + e0]     = acc[k][0];
            *(float4*)&hb[fi * Ee + e0 + 4] = acc[k][1];
        }
    }
}

extern "C" void kernel_launch(void* const* d_in, const int* in_sizes, int n_in,
                              void* d_out, int out_size, void* d_ws, size_t ws_size,
                              hipStream_t stream) {
    const float* g     = (const float*)d_in[0];
    const float* h     = (const float*)d_in[1];
    const float* W_in  = (const float*)d_in[2];
    const float* W_out = (const float*)d_in[3];
    const float* bias  = (const float*)d_in[4];
    float* out = (float*)d_out;

    dim3 grid1(Bz / BT, Ff);   // (128, 50)
    // stage 1: h_out -> d_out
    field_gemm<<<grid1, 128, 0, stream>>>(h, out, W_out, nullptr);
    // stage 2: aggr, in place over d_out (one wave per batch)
    aggr_inplace<<<Bz / 2, 128, 0, stream>>>(g, out);
    // stage 3: a = W_in * aggr + bias, in place over d_out
    field_gemm<<<grid1, 128, 0, stream>>>(out, out, W_in, bias);
}

// Round 2
// 653.885 us; speedup vs baseline: 1.0621x; 1.0320x over previous
//
#include <hip/hip_runtime.h>
#include <stdint.h>

// GraphLayer: B=16384, F=50, E=64, all fp32.
//   h_out[b,f,i] = sum_j W_out[f,i,j] * h[b,f,j]
//   aggr[b,f,e]  = sum_g g[b,f,g] * h_out[b,g,e]
//   a[b,f,i]     = sum_j W_in[f,i,j] * aggr[b,f,j] + bias[i]
//
// Round 4: field_gemm was latency-bound at 14.6% occupancy (128 thr, 52 KB
// LDS -> 3 blocks x 2 waves = 1.5 waves/SIMD; VALU 40% / HBM 25% / conflicts 0
// -- nothing saturated).  Keep the 8x8 per-thread tile (1 B LDS-read per FMA,
// LDS-pipe floor ~64 us) but:
//   * 256 threads, BT=256 (block tile 64i x 256b)
//   * no pad; XOR-swizzle 16B chunks (c ^= row&7) => LDS = 16K + 64K = 80 KB
//     exactly -> 2 blocks/CU = 8 waves/CU, two independent blocks overlap
//     stage/compute phases
//   * global_load_lds (16 B) staging with PRE-SWIZZLED GLOBAL source (LDS
//     dest must stay linear: uniform base + lane*16) -- kills the
//     load->VGPR->ds_write round-trip and frees the LDS write pipe.
// Every compute b128 read has its 8 lane-rows distinct mod 8, so the XOR
// spreads them over all 32 banks: conflict-free.

static constexpr int Bz  = 16384;
static constexpr int Ff  = 50;
static constexpr int Ee  = 64;
static constexpr int BT  = 256;   // batch tile for per-field GEMM

__device__ __forceinline__ void fma4(float4& a, float s, const float4& v) {
    a.x += s * v.x; a.y += s * v.y; a.z += s * v.z; a.w += s * v.w;
}

// async global->LDS, 16 B per lane.  LDS dest is wave-uniform base + lane*16
// (our dests are linear in thread id, so passing the per-lane pointer is
// consistent with the HW behavior).
__device__ __forceinline__ void gld_lds16(const float* gsrc, float* ldst) {
    __builtin_amdgcn_global_load_lds(
        (const __attribute__((address_space(1))) uint32_t*)gsrc,
        (__attribute__((address_space(3))) uint32_t*)ldst, 16, 0, 0);
}

// dst[b,f,i] = sum_j W[f,i,j]*src[b,f,j] (+ bias[i]).  In-place (src==dst)
// safe: all global reads land in LDS before the barrier; stores after; each
// (b,f,:) row is owned by exactly one block.
// LDS layout: f4-slot (row r, chunk c) holds global chunk (r, c ^ (r&7)).
// Compute read of global column-quad jq at row r: LDS[r][jq ^ (r&7)].
__global__ __launch_bounds__(256, 2)
void field_gemm(const float* __restrict__ src, float* __restrict__ dst,
                const float* __restrict__ W, const float* __restrict__ bias) {
    __shared__ float lds[Ee * Ee + BT * Ee];   // 4096 + 16384 floats = 80 KB
    float* W_lds = lds;                        // [64][64] swizzled
    float* h_lds = lds + Ee * Ee;              // [256][64] swizzled
    const int f  = blockIdx.y;
    const int b0 = blockIdx.x * BT;
    const int t  = threadIdx.x;

    // stage W[f]: 1024 float4 (4 per thread), linear LDS, swizzled source
    const float4* Wf4 = (const float4*)(W + f * (Ee * Ee));
#pragma unroll
    for (int k = 0; k < 4; ++k) {
        int q = k * 256 + t;
        int r = q >> 4, c = q & 15;
        gld_lds16((const float*)&Wf4[r * 16 + (c ^ (r & 7))], &W_lds[q * 4]);
    }
    // stage src tile: 4096 float4 (16 per thread), linear LDS, swizzled source
    const float4* s4 = (const float4*)src;
#pragma unroll
    for (int k = 0; k < 16; ++k) {
        int q = k * 256 + t;
        int r = q >> 4, c = q & 15;
        gld_lds16((const float*)&s4[(b0 + r) * (Ff * Ee / 4) + f * 16 + (c ^ (r & 7))],
                  &h_lds[q * 4]);
    }
    __syncthreads();   // compiler drains vmcnt(0) before s_barrier

    const int ti = t & 7;    // i  = ti + 8*ii   (row&7 = ti: distinct per lane)
    const int tb = t >> 3;   // bb = tb + 32*kb  (row&7 = tb&7: distinct per lane)
    const int tb7 = tb & 7;
    const float4* wp = (const float4*)W_lds;
    const float4* hp = (const float4*)h_lds;

    float acc[8][8];
#pragma unroll
    for (int ii = 0; ii < 8; ++ii)
#pragma unroll
        for (int kb = 0; kb < 8; ++kb) acc[ii][kb] = 0.f;

#pragma unroll 2
    for (int jq = 0; jq < 16; ++jq) {          // j = 4*jq .. 4*jq+3
        float4 w4[8], h4[8];
#pragma unroll
        for (int ii = 0; ii < 8; ++ii)
            w4[ii] = wp[(ti + 8 * ii) * 16 + (jq ^ ti)];
#pragma unroll
        for (int kb = 0; kb < 8; ++kb)
            h4[kb] = hp[(tb + 32 * kb) * 16 + (jq ^ tb7)];
#pragma unroll
        for (int ii = 0; ii < 8; ++ii)
#pragma unroll
            for (int kb = 0; kb < 8; ++kb) {
                acc[ii][kb] += w4[ii].x * h4[kb].x;
                acc[ii][kb] += w4[ii].y * h4[kb].y;
                acc[ii][kb] += w4[ii].z * h4[kb].z;
                acc[ii][kb] += w4[ii].w * h4[kb].w;
            }
    }

    // stores: per inst, wave covers 8 rows x 32 B contiguous; consecutive ii
    // fill neighboring 32 B of the same rows -> L2 write-combines (round-1
    // WRITE_SIZE was exactly ideal).
#pragma unroll
    for (int ii = 0; ii < 8; ++ii) {
        const int i  = ti + 8 * ii;
        const float bv = bias ? bias[i] : 0.0f;
#pragma unroll
        for (int kb = 0; kb < 8; ++kb) {
            const int bb = tb + 32 * kb;
            dst[(b0 + bb) * (Ff * Ee) + f * Ee + i] = acc[ii][kb] + bv;
        }
    }
}

// aggr[b,f,e] = sum_g g[b,f,g] * ho[b,g,e], in place over ho (d_out).
// (unchanged from round 3 -- dropped out of the top-5; next-round target)
static constexpr int HOP = 52 * Ee;        // 3328 floats: 50 rows + 2 pad rows
static constexpr int GPD = 2560;           // 2500 + 60 pad floats
static constexpr int WRG = HOP + GPD;      // 5888 floats per wave

__global__ __launch_bounds__(128, 2)
void aggr_inplace(const float* __restrict__ g, float* __restrict__ ho) {
    __shared__ float lds[2 * WRG];         // 47.1 KB -> 3 blocks/CU
    const int t    = threadIdx.x;
    const int wid  = t >> 6;
    const int lane = t & 63;
    const int b    = blockIdx.x * 2 + wid;
    float* ho_sh = &lds[wid * WRG];
    float* g_sh  = ho_sh + HOP;

    const float4* hosrc = (const float4*)(ho + (size_t)b * (Ff * Ee)); // 800 f4
    const float4* gsrc  = (const float4*)(g  + (size_t)b * (Ff * Ff)); // 625 f4
#pragma unroll
    for (int k = 0; k < 13; ++k) {
        int q = k * 64 + lane;
        if (q < Ff * Ee / 4) *(float4*)&ho_sh[q * 4] = hosrc[q];
    }
#pragma unroll
    for (int k = 0; k < 10; ++k) {
        int q = k * 64 + lane;
        if (q < (Ff * Ff + 3) / 4) *(float4*)&g_sh[q * 4] = gsrc[q];
    }
    // zero pads (must be zero, not garbage: garbage could be NaN/Inf and
    // NaN*0 != 0)
    *(float2*)&ho_sh[Ff * Ee + lane * 2] = make_float2(0.f, 0.f);   // rows 50,51
    if (lane < 30) *(float2*)&g_sh[Ff * Ff + lane * 2] = make_float2(0.f, 0.f);
    __syncthreads();

    const int te = lane & 7;
    const int tf = lane >> 3;
    const int e0 = te * 8;
    float4 acc[7][2];
#pragma unroll
    for (int k = 0; k < 7; ++k) {
        acc[k][0] = make_float4(0.f, 0.f, 0.f, 0.f);
        acc[k][1] = make_float4(0.f, 0.f, 0.f, 0.f);
    }

#pragma unroll 2
    for (int g0 = 0; g0 < 52; g0 += 4) {
        float4 ho4[4][2];
#pragma unroll
        for (int q = 0; q < 4; ++q) {
            ho4[q][0] = *(const float4*)&ho_sh[(g0 + q) * Ee + e0];
            ho4[q][1] = *(const float4*)&ho_sh[(g0 + q) * Ee + e0 + 4];
        }
#pragma unroll
        for (int k = 0; k < 7; ++k) {
            int fi = tf * 7 + k;
            fi = (fi < Ff) ? fi : (Ff - 1);   // clamp; duplicate rows not stored
            const float2 ga = *(const float2*)&g_sh[fi * Ff + g0];
            const float2 gb = *(const float2*)&g_sh[fi * Ff + g0 + 2];
            fma4(acc[k][0], ga.x,  ho4[0][0]); fma4(acc[k][1], ga.x,  ho4[0][1]);
            fma4(acc[k][0], ga.y,  ho4[1][0]); fma4(acc[k][1], ga.y,  ho4[1][1]);
            fma4(acc[k][0], gb.x,  ho4[2][0]); fma4(acc[k][1], gb.x,  ho4[2][1]);
            fma4(acc[k][0], gb.y,  ho4[3][0]); fma4(acc[k][1], gb.y,  ho4[3][1]);
        }
    }

    float* hb = ho + (size_t)b * (Ff * Ee);
#pragma unroll
    for (int k = 0; k < 7; ++k) {
        const int fi = tf * 7 + k;          // unclamped for the store guard
        if (fi < Ff) {
            *(float4*)&hb[fi * Ee + e0]     = acc[k][0];
            *(float4*)&hb[fi * Ee + e0 + 4] = acc[k][1];
        }
    }
}

extern "C" void kernel_launch(void* const* d_in, const int* in_sizes, int n_in,
                              void* d_out, int out_size, void* d_ws, size_t ws_size,
                              hipStream_t stream) {
    const float* g     = (const float*)d_in[0];
    const float* h     = (const float*)d_in[1];
    const float* W_in  = (const float*)d_in[2];
    const float* W_out = (const float*)d_in[3];
    const float* bias  = (const float*)d_in[4];
    float* out = (float*)d_out;

    dim3 grid1(Bz / BT, Ff);   // (64, 50)
    // stage 1: h_out -> d_out
    field_gemm<<<grid1, 256, 0, stream>>>(h, out, W_out, nullptr);
    // stage 2: aggr, in place over d_out (one wave per batch)
    aggr_inplace<<<Bz / 2, 128, 0, stream>>>(g, out);
    // stage 3: a = W_in * aggr + bias, in place over d_out
    field_gemm<<<grid1, 256, 0, stream>>>(out, out, W_in, bias);
}